// Round 2
// baseline (507.265 us; speedup 1.0000x reference)
//
#include <hip/hip_runtime.h>
#include <hip/hip_bf16.h>

// CausalMHA fused: x@Wqkv -> causal flash attention -> @Wout
// B=2 S=2048 D=2048 H=16 Dh=128. All heavy math in bf16 MFMA (16x16x32).
// Workspace layout (needs 128 MiB):
//   xb    @ 0        : bf16 [4096][2048]   (16.78 MB)
//   wqkvT @ 16777216 : bf16 [6144][2048]   (25.17 MB)
//   woutT @ 41943040 : bf16 [2048][2048]   ( 8.39 MB)
//   qkvb  @ 50331648 : bf16 [4096][6144]   (50.33 MB)
//   vT    @100663296 : bf16 [32*128][2048] (16.78 MB)
//   ob    @117440512 : bf16 [4096][2048]   (16.78 MB)

#define SEQ 2048
#define DM 2048
#define NQKV 6144
#define DH 128

typedef __attribute__((ext_vector_type(8))) short bf16x8;
typedef __attribute__((ext_vector_type(4))) float f32x4;

__device__ __forceinline__ f32x4 mfma16(bf16x8 a, bf16x8 b, f32x4 c) {
  return __builtin_amdgcn_mfma_f32_16x16x32_bf16(a, b, c, 0, 0, 0);
}

__device__ __forceinline__ void gload_lds16(const void* g, void* l) {
  __builtin_amdgcn_global_load_lds(
      (const __attribute__((address_space(1))) unsigned int*)g,
      (__attribute__((address_space(3))) unsigned int*)l, 16, 0, 0);
}

// ---------------- cast fp32 -> bf16, 4 elems/thread ----------------
__global__ __launch_bounds__(256) void cast_f32_bf16(
    const float* __restrict__ in, __hip_bfloat16* __restrict__ out, int n4) {
  int i = blockIdx.x * 256 + threadIdx.x;
  if (i >= n4) return;
  float4 f = reinterpret_cast<const float4*>(in)[i];
  union { __hip_bfloat16 h[4]; unsigned long long u; } o;
  o.h[0] = __float2bfloat16(f.x); o.h[1] = __float2bfloat16(f.y);
  o.h[2] = __float2bfloat16(f.z); o.h[3] = __float2bfloat16(f.w);
  reinterpret_cast<unsigned long long*>(out)[i] = o.u;
}

// ------------- transpose + cast: fp32 [R][C] -> bf16 [C][R] -------------
__global__ __launch_bounds__(256) void transpose_cast(
    const float* __restrict__ in, __hip_bfloat16* __restrict__ out, int R, int C) {
  __shared__ float t[32][33];
  int c0 = blockIdx.x * 32, r0 = blockIdx.y * 32;
  int tx = threadIdx.x, ty = threadIdx.y;
#pragma unroll
  for (int i = 0; i < 4; ++i)
    t[ty + i * 8][tx] = in[(size_t)(r0 + ty + i * 8) * C + c0 + tx];
  __syncthreads();
#pragma unroll
  for (int i = 0; i < 4; ++i)
    out[(size_t)(c0 + ty + i * 8) * R + r0 + tx] = __float2bfloat16(t[tx][ty + i * 8]);
}

// ---- transpose V region of qkv [b,s,(2*DM+h*DH+d)] -> vT[(b*16+h)*128+d][s] ----
__global__ __launch_bounds__(256) void transpose_v(
    const __hip_bfloat16* __restrict__ qkv, __hip_bfloat16* __restrict__ vT) {
  __shared__ __hip_bfloat16 t[32][33];
  int bh = blockIdx.z;
  int b = bh >> 4, h = bh & 15;
  int s0 = blockIdx.x * 32, d0 = blockIdx.y * 32;
  int tx = threadIdx.x, ty = threadIdx.y;
#pragma unroll
  for (int i = 0; i < 4; ++i)
    t[ty + i * 8][tx] =
        qkv[(size_t)(b * SEQ + s0 + ty + i * 8) * NQKV + 2 * DM + h * DH + d0 + tx];
  __syncthreads();
#pragma unroll
  for (int i = 0; i < 4; ++i)
    vT[(size_t)(bh * DH + d0 + ty + i * 8) * SEQ + s0 + tx] = t[tx][ty + i * 8];
}

// ---------------- GEMM: C[M][N] = A[M][K] * Bt[N][K]^T ----------------
// m97 structure: 128x128 tile, BK=64, 4 waves (2x2), each wave 64x64 (4x4 frags).
// EPI 0: bf16 out; EPI 1: f32 out.
template <int EPI>
__global__ __launch_bounds__(256) void gemm_bt(
    const __hip_bfloat16* __restrict__ A, const __hip_bfloat16* __restrict__ Bt,
    void* __restrict__ Cout, int M, int N, int K) {
  __shared__ alignas(16) __hip_bfloat16 As[128 * 64];
  __shared__ alignas(16) __hip_bfloat16 Bs[128 * 64];
  const int tid = threadIdx.x;
  const int lane = tid & 63;
  const int w = tid >> 6, wr = w >> 1, wc = w & 1;
  const int lr = lane & 15, lg = lane >> 4;
  const int m0 = blockIdx.y * 128, n0 = blockIdx.x * 128;
  f32x4 acc[4][4] = {};
  for (int k0 = 0; k0 < K; k0 += 64) {
#pragma unroll
    for (int it = 0; it < 4; ++it) {
      int e = (it * 256 + tid) * 8;          // element index, row = e/64, col = e%64
      int row = e >> 6, col = e & 63;
      gload_lds16(A + (size_t)(m0 + row) * K + k0 + col, (char*)As + (size_t)e * 2);
      gload_lds16(Bt + (size_t)(n0 + row) * K + k0 + col, (char*)Bs + (size_t)e * 2);
    }
    __syncthreads();
#pragma unroll
    for (int ks = 0; ks < 2; ++ks) {
      bf16x8 af[4], bfr[4];
#pragma unroll
      for (int m = 0; m < 4; ++m)
        af[m] = *(const bf16x8*)((const char*)As +
                                 (wr * 64 + m * 16 + lr) * 128 + ks * 64 + lg * 16);
#pragma unroll
      for (int n = 0; n < 4; ++n)
        bfr[n] = *(const bf16x8*)((const char*)Bs +
                                  (wc * 64 + n * 16 + lr) * 128 + ks * 64 + lg * 16);
#pragma unroll
      for (int m = 0; m < 4; ++m)
#pragma unroll
        for (int n = 0; n < 4; ++n)
          acc[m][n] = mfma16(af[m], bfr[n], acc[m][n]);
    }
    __syncthreads();
  }
  const int crow = m0 + wr * 64, ccol = n0 + wc * 64;
#pragma unroll
  for (int m = 0; m < 4; ++m)
#pragma unroll
    for (int n = 0; n < 4; ++n)
#pragma unroll
      for (int j = 0; j < 4; ++j) {
        int r = crow + m * 16 + lg * 4 + j;
        int c = ccol + n * 16 + lr;
        if (EPI == 0)
          ((__hip_bfloat16*)Cout)[(size_t)r * N + c] = __float2bfloat16(acc[m][n][j]);
        else
          ((float*)Cout)[(size_t)r * N + c] = acc[m][n][j];
      }
}

// ---------------- causal flash attention ----------------
// Block: 256 thr (4 waves), QBLK=64 (16 q-rows/wave), KVBLK=64.
// K staged [64][128]bf16 swizzled; V^T staged [128][64]bf16 swizzled.
// grid: (S/64, B*H)
__global__ __launch_bounds__(256) void attn_causal(
    const __hip_bfloat16* __restrict__ qkv, const __hip_bfloat16* __restrict__ vT,
    __hip_bfloat16* __restrict__ O) {
  __shared__ alignas(16) __hip_bfloat16 Ks[64 * 128];
  __shared__ alignas(16) __hip_bfloat16 Vs[128 * 64];
  __shared__ alignas(16) __hip_bfloat16 Ps[4][16 * 64];
  const int tid = threadIdx.x, lane = tid & 63, w = tid >> 6;
  const int lr = lane & 15, lg = lane >> 4;
  const int qt = blockIdx.x, bh = blockIdx.y;
  const int b = bh >> 4, h = bh & 15;
  const int q0 = qt * 64;
  // Q fragments in registers (16 rows x 128 d per wave)
  const int qrow = q0 + w * 16 + lr;
  const __hip_bfloat16* qp = qkv + (size_t)(b * SEQ + qrow) * NQKV + h * DH;
  bf16x8 qf[4];
#pragma unroll
  for (int ks = 0; ks < 4; ++ks) qf[ks] = *(const bf16x8*)(qp + ks * 32 + lg * 8);
  f32x4 of[8] = {};
  float mrun[4], lrun[4];
#pragma unroll
  for (int j = 0; j < 4; ++j) { mrun[j] = -1e30f; lrun[j] = 0.f; }
  const float scale = 0.08838834764831845f;  // 1/sqrt(128)
  const int myq = q0 + w * 16 + lg * 4;      // +j gives this lane's acc row

  for (int t = 0; t <= qt; ++t) {
    const int kv0 = t * 64;
    // stage K tile: 64 rows x 256B, source-swizzled so swizzled reads are conflict-free
#pragma unroll
    for (int it = 0; it < 4; ++it) {
      int g = it * 256 + tid;
      int r = g >> 4, sl = g & 15;
      int ssl = sl ^ (r & 7);
      gload_lds16(qkv + (size_t)(b * SEQ + kv0 + r) * NQKV + DM + h * DH + ssl * 8,
                  (char*)Ks + (size_t)g * 16);
    }
    // stage V^T tile: 128 rows x 128B
#pragma unroll
    for (int it = 0; it < 4; ++it) {
      int g = it * 256 + tid;
      int r = g >> 3, sl = g & 7;
      int ssl = sl ^ (r & 7);
      gload_lds16(vT + (size_t)(bh * DH + r) * SEQ + kv0 + ssl * 8,
                  (char*)Vs + (size_t)g * 16);
    }
    __syncthreads();

    // S = Q K^T  (4 col-tiles of 16 kv)
    f32x4 sacc[4] = {};
#pragma unroll
    for (int n = 0; n < 4; ++n) {
      const int krow = n * 16 + lr;
      const char* kbase = (const char*)Ks + krow * 256;
#pragma unroll
      for (int ks = 0; ks < 4; ++ks) {
        int c = ks * 64 + lg * 16;
        bf16x8 kb = *(const bf16x8*)(kbase + (c ^ ((krow & 7) << 4)));
        sacc[n] = mfma16(qf[ks], kb, sacc[n]);
      }
    }
    // scale + causal mask (only diagonal tile)
    const bool dg = (t == qt);
#pragma unroll
    for (int n = 0; n < 4; ++n)
#pragma unroll
      for (int j = 0; j < 4; ++j) {
        float v = sacc[n][j] * scale;
        if (dg && (kv0 + n * 16 + lr > myq + j)) v = -1e30f;
        sacc[n][j] = v;
      }
    // online softmax: row max over 4 tiles + 16-lane butterfly
    float pm[4];
#pragma unroll
    for (int j = 0; j < 4; ++j)
      pm[j] = fmaxf(fmaxf(sacc[0][j], sacc[1][j]), fmaxf(sacc[2][j], sacc[3][j]));
#pragma unroll
    for (int d = 1; d < 16; d <<= 1)
#pragma unroll
      for (int j = 0; j < 4; ++j) pm[j] = fmaxf(pm[j], __shfl_xor(pm[j], d));
    float corr[4], rs[4];
#pragma unroll
    for (int j = 0; j < 4; ++j) {
      float mn = fmaxf(mrun[j], pm[j]);
      corr[j] = __expf(mrun[j] - mn);
      mrun[j] = mn;
      rs[j] = 0.f;
    }
#pragma unroll
    for (int n = 0; n < 4; ++n)
#pragma unroll
      for (int j = 0; j < 4; ++j) {
        float p = __expf(sacc[n][j] - mrun[j]);
        sacc[n][j] = p;
        rs[j] += p;
      }
#pragma unroll
    for (int d = 1; d < 16; d <<= 1)
#pragma unroll
      for (int j = 0; j < 4; ++j) rs[j] += __shfl_xor(rs[j], d);
#pragma unroll
    for (int j = 0; j < 4; ++j) lrun[j] = lrun[j] * corr[j] + rs[j];
#pragma unroll
    for (int nn = 0; nn < 8; ++nn)
#pragma unroll
      for (int j = 0; j < 4; ++j) of[nn][j] *= corr[j];

    // P -> per-wave LDS (bf16, swizzled rows of 128B), then read as A-fragments
    __hip_bfloat16* pw = &Ps[w][0];
#pragma unroll
    for (int j = 0; j < 4; ++j) {
      int prow = lg * 4 + j;
      char* pb = (char*)pw + prow * 128;
#pragma unroll
      for (int n = 0; n < 4; ++n) {
        int c = (n * 16 + lr) * 2;
        *(__hip_bfloat16*)(pb + (c ^ ((prow & 7) << 4))) = __float2bfloat16(sacc[n][j]);
      }
    }
    // O += P V   (8 d-tiles of 16)
#pragma unroll
    for (int kvs = 0; kvs < 2; ++kvs) {
      int c = kvs * 64 + lg * 16;
      bf16x8 pa = *(const bf16x8*)((const char*)pw + lr * 128 + (c ^ ((lr & 7) << 4)));
#pragma unroll
      for (int nn = 0; nn < 8; ++nn) {
        int vrow = nn * 16 + lr;
        bf16x8 vb =
            *(const bf16x8*)((const char*)Vs + vrow * 128 + (c ^ ((vrow & 7) << 4)));
        of[nn] = mfma16(pa, vb, of[nn]);
      }
    }
    __syncthreads();
  }
  // epilogue: normalize + write bf16 [4096][2048]
#pragma unroll
  for (int j = 0; j < 4; ++j) {
    float inv = 1.0f / lrun[j];
    size_t orow = (size_t)(b * SEQ + q0 + w * 16 + lg * 4 + j);
    __hip_bfloat16* op = O + orow * DM + h * DH;
#pragma unroll
    for (int nn = 0; nn < 8; ++nn)
      op[nn * 16 + lr] = __float2bfloat16(of[nn][j] * inv);
  }
}

extern "C" void kernel_launch(void* const* d_in, const int* in_sizes, int n_in,
                              void* d_out, int out_size, void* d_ws, size_t ws_size,
                              hipStream_t stream) {
  const float* x = (const float*)d_in[0];
  const float* Wqkv = (const float*)d_in[1];
  const float* Wout = (const float*)d_in[2];
  float* out = (float*)d_out;
  char* ws = (char*)d_ws;
  __hip_bfloat16* xb    = (__hip_bfloat16*)(ws + 0);
  __hip_bfloat16* wqkvT = (__hip_bfloat16*)(ws + (size_t)16777216);
  __hip_bfloat16* woutT = (__hip_bfloat16*)(ws + (size_t)41943040);
  __hip_bfloat16* qkvb  = (__hip_bfloat16*)(ws + (size_t)50331648);
  __hip_bfloat16* vT    = (__hip_bfloat16*)(ws + (size_t)100663296);
  __hip_bfloat16* ob    = (__hip_bfloat16*)(ws + (size_t)117440512);

  cast_f32_bf16<<<dim3(8192), dim3(256), 0, stream>>>(x, xb, 8388608 / 4);
  transpose_cast<<<dim3(192, 64), dim3(32, 8), 0, stream>>>(Wqkv, wqkvT, 2048, 6144);
  transpose_cast<<<dim3(64, 64), dim3(32, 8), 0, stream>>>(Wout, woutT, 2048, 2048);
  gemm_bt<0><<<dim3(48, 32), dim3(256), 0, stream>>>(xb, wqkvT, qkvb, 4096, 6144, 2048);
  transpose_v<<<dim3(64, 4, 32), dim3(32, 8), 0, stream>>>(qkvb, vT);
  attn_causal<<<dim3(32, 32), dim3(256), 0, stream>>>(qkvb, vT, ob);
  gemm_bt<1><<<dim3(16, 32), dim3(256), 0, stream>>>(ob, woutT, out, 4096, 2048, 2048);
}

// Round 4
// 435.200 us; speedup vs baseline: 1.1656x; 1.1656x over previous
//
#include <hip/hip_runtime.h>
#include <hip/hip_bf16.h>

// CausalMHA fused: x@Wqkv -> causal flash attention -> @Wout
// B=2 S=2048 D=2048 H=16 Dh=128. All heavy math in bf16 MFMA (16x16x32).
// R2: attention restructured — pair-balanced q-tiles (p, 31-p) per block,
//     KVBLK=128 staged once and shared by both q-tiles, defer-max (T13).
// Workspace layout (needs 128 MiB):
//   xb    @ 0        : bf16 [4096][2048]   (16.78 MB)
//   wqkvT @ 16777216 : bf16 [6144][2048]   (25.17 MB)
//   woutT @ 41943040 : bf16 [2048][2048]   ( 8.39 MB)
//   qkvb  @ 50331648 : bf16 [4096][6144]   (50.33 MB)
//   vT    @100663296 : bf16 [32*128][2048] (16.78 MB)
//   ob    @117440512 : bf16 [4096][2048]   (16.78 MB)

#define SEQ 2048
#define DM 2048
#define NQKV 6144
#define DH 128

typedef __attribute__((ext_vector_type(8))) short bf16x8;
typedef __attribute__((ext_vector_type(4))) float f32x4;

__device__ __forceinline__ f32x4 mfma16(bf16x8 a, bf16x8 b, f32x4 c) {
  return __builtin_amdgcn_mfma_f32_16x16x32_bf16(a, b, c, 0, 0, 0);
}

__device__ __forceinline__ void gload_lds16(const void* g, void* l) {
  __builtin_amdgcn_global_load_lds(
      (const __attribute__((address_space(1))) unsigned int*)g,
      (__attribute__((address_space(3))) unsigned int*)l, 16, 0, 0);
}

// ---------------- cast fp32 -> bf16, 4 elems/thread ----------------
__global__ __launch_bounds__(256) void cast_f32_bf16(
    const float* __restrict__ in, __hip_bfloat16* __restrict__ out, int n4) {
  int i = blockIdx.x * 256 + threadIdx.x;
  if (i >= n4) return;
  float4 f = reinterpret_cast<const float4*>(in)[i];
  union { __hip_bfloat16 h[4]; unsigned long long u; } o;
  o.h[0] = __float2bfloat16(f.x); o.h[1] = __float2bfloat16(f.y);
  o.h[2] = __float2bfloat16(f.z); o.h[3] = __float2bfloat16(f.w);
  reinterpret_cast<unsigned long long*>(out)[i] = o.u;
}

// ------------- transpose + cast: fp32 [R][C] -> bf16 [C][R] -------------
__global__ __launch_bounds__(256) void transpose_cast(
    const float* __restrict__ in, __hip_bfloat16* __restrict__ out, int R, int C) {
  __shared__ float t[32][33];
  int c0 = blockIdx.x * 32, r0 = blockIdx.y * 32;
  int tx = threadIdx.x, ty = threadIdx.y;
#pragma unroll
  for (int i = 0; i < 4; ++i)
    t[ty + i * 8][tx] = in[(size_t)(r0 + ty + i * 8) * C + c0 + tx];
  __syncthreads();
#pragma unroll
  for (int i = 0; i < 4; ++i)
    out[(size_t)(c0 + ty + i * 8) * R + r0 + tx] = __float2bfloat16(t[tx][ty + i * 8]);
}

// ---- transpose V region of qkv [b,s,(2*DM+h*DH+d)] -> vT[(b*16+h)*128+d][s] ----
__global__ __launch_bounds__(256) void transpose_v(
    const __hip_bfloat16* __restrict__ qkv, __hip_bfloat16* __restrict__ vT) {
  __shared__ __hip_bfloat16 t[32][33];
  int bh = blockIdx.z;
  int b = bh >> 4, h = bh & 15;
  int s0 = blockIdx.x * 32, d0 = blockIdx.y * 32;
  int tx = threadIdx.x, ty = threadIdx.y;
#pragma unroll
  for (int i = 0; i < 4; ++i)
    t[ty + i * 8][tx] =
        qkv[(size_t)(b * SEQ + s0 + ty + i * 8) * NQKV + 2 * DM + h * DH + d0 + tx];
  __syncthreads();
#pragma unroll
  for (int i = 0; i < 4; ++i)
    vT[(size_t)(bh * DH + d0 + ty + i * 8) * SEQ + s0 + tx] = t[tx][ty + i * 8];
}

// ---------------- GEMM: C[M][N] = A[M][K] * Bt[N][K]^T ----------------
// m97 structure: 128x128 tile, BK=64, 4 waves (2x2), each wave 64x64 (4x4 frags).
template <int EPI>
__global__ __launch_bounds__(256) void gemm_bt(
    const __hip_bfloat16* __restrict__ A, const __hip_bfloat16* __restrict__ Bt,
    void* __restrict__ Cout, int M, int N, int K) {
  __shared__ alignas(16) __hip_bfloat16 As[128 * 64];
  __shared__ alignas(16) __hip_bfloat16 Bs[128 * 64];
  const int tid = threadIdx.x;
  const int lane = tid & 63;
  const int w = tid >> 6, wr = w >> 1, wc = w & 1;
  const int lr = lane & 15, lg = lane >> 4;
  const int m0 = blockIdx.y * 128, n0 = blockIdx.x * 128;
  f32x4 acc[4][4] = {};
  for (int k0 = 0; k0 < K; k0 += 64) {
#pragma unroll
    for (int it = 0; it < 4; ++it) {
      int e = (it * 256 + tid) * 8;          // element index, row = e/64, col = e%64
      int row = e >> 6, col = e & 63;
      gload_lds16(A + (size_t)(m0 + row) * K + k0 + col, (char*)As + (size_t)e * 2);
      gload_lds16(Bt + (size_t)(n0 + row) * K + k0 + col, (char*)Bs + (size_t)e * 2);
    }
    __syncthreads();
#pragma unroll
    for (int ks = 0; ks < 2; ++ks) {
      bf16x8 af[4], bfr[4];
#pragma unroll
      for (int m = 0; m < 4; ++m)
        af[m] = *(const bf16x8*)((const char*)As +
                                 (wr * 64 + m * 16 + lr) * 128 + ks * 64 + lg * 16);
#pragma unroll
      for (int n = 0; n < 4; ++n)
        bfr[n] = *(const bf16x8*)((const char*)Bs +
                                  (wc * 64 + n * 16 + lr) * 128 + ks * 64 + lg * 16);
#pragma unroll
      for (int m = 0; m < 4; ++m)
#pragma unroll
        for (int n = 0; n < 4; ++n)
          acc[m][n] = mfma16(af[m], bfr[n], acc[m][n]);
    }
    __syncthreads();
  }
  const int crow = m0 + wr * 64, ccol = n0 + wc * 64;
#pragma unroll
  for (int m = 0; m < 4; ++m)
#pragma unroll
    for (int n = 0; n < 4; ++n)
#pragma unroll
      for (int j = 0; j < 4; ++j) {
        int r = crow + m * 16 + lg * 4 + j;
        int c = ccol + n * 16 + lr;
        if (EPI == 0)
          ((__hip_bfloat16*)Cout)[(size_t)r * N + c] = __float2bfloat16(acc[m][n][j]);
        else
          ((float*)Cout)[(size_t)r * N + c] = acc[m][n][j];
      }
}

// ---------------- causal flash attention (pair-balanced, KVBLK=128) ----------------
// Block: 256 thr (4 waves). Block p handles q-tiles {p, 31-p} (64 rows each,
// 16 rows/wave). Each 128-row KV tile is staged ONCE and consumed by both
// q-tiles. LDS: Ks[128][128] + Vs[128][128] + Ps[4][16][128] = 80 KB -> 2 blk/CU.
__device__ __forceinline__ void attn_tile(
    const bf16x8 (&qf)[4], f32x4 (&of)[8], float (&mrun)[4], float (&lrun)[4],
    const char* Ks, const char* Vs, char* pw,
    int lr, int lg, int kv0, int myq, bool lastmask, float scale) {
  f32x4 sacc[8];
#pragma unroll
  for (int n = 0; n < 8; ++n) sacc[n] = f32x4{0.f, 0.f, 0.f, 0.f};
  // S = Q K^T  (8 col-tiles of 16 kv)
#pragma unroll
  for (int n = 0; n < 8; ++n) {
    const int krow = n * 16 + lr;
    const char* kbase = Ks + krow * 256;
#pragma unroll
    for (int ks = 0; ks < 4; ++ks) {
      int c = ks * 64 + lg * 16;
      bf16x8 kb = *(const bf16x8*)(kbase + (c ^ ((krow & 7) << 4)));
      sacc[n] = mfma16(qf[ks], kb, sacc[n]);
    }
  }
  // scale + causal mask (last tile only)
#pragma unroll
  for (int n = 0; n < 8; ++n)
#pragma unroll
    for (int j = 0; j < 4; ++j) {
      float v = sacc[n][j] * scale;
      if (lastmask && (kv0 + n * 16 + lr > myq + j)) v = -1e30f;
      sacc[n][j] = v;
    }
  // row max (8 tiles in-lane + 16-lane butterfly)
  float pm[4];
#pragma unroll
  for (int j = 0; j < 4; ++j) {
    float a = fmaxf(fmaxf(sacc[0][j], sacc[1][j]), fmaxf(sacc[2][j], sacc[3][j]));
    float bx = fmaxf(fmaxf(sacc[4][j], sacc[5][j]), fmaxf(sacc[6][j], sacc[7][j]));
    pm[j] = fmaxf(a, bx);
  }
#pragma unroll
  for (int d = 1; d < 16; d <<= 1)
#pragma unroll
    for (int j = 0; j < 4; ++j) pm[j] = fmaxf(pm[j], __shfl_xor(pm[j], d));
  // defer-max (T13): only rescale when max grew by > 8
  bool big = false;
#pragma unroll
  for (int j = 0; j < 4; ++j) big = big || (pm[j] > mrun[j] + 8.0f);
  if (__any(big)) {
#pragma unroll
    for (int j = 0; j < 4; ++j) {
      float mn = fmaxf(mrun[j], pm[j]);
      float corr = __expf(mrun[j] - mn);
      mrun[j] = mn;
      lrun[j] *= corr;
#pragma unroll
      for (int nn = 0; nn < 8; ++nn) of[nn][j] *= corr;
    }
  }
  float rs[4] = {0.f, 0.f, 0.f, 0.f};
#pragma unroll
  for (int n = 0; n < 8; ++n)
#pragma unroll
    for (int j = 0; j < 4; ++j) {
      float pv = __expf(sacc[n][j] - mrun[j]);
      sacc[n][j] = pv;
      rs[j] += pv;
    }
#pragma unroll
  for (int d = 1; d < 16; d <<= 1)
#pragma unroll
    for (int j = 0; j < 4; ++j) rs[j] += __shfl_xor(rs[j], d);
#pragma unroll
  for (int j = 0; j < 4; ++j) lrun[j] += rs[j];
  // P -> per-wave LDS (bf16, swizzled 256B rows)
#pragma unroll
  for (int j = 0; j < 4; ++j) {
    int prow = lg * 4 + j;
    char* pb = pw + prow * 256;
#pragma unroll
    for (int n = 0; n < 8; ++n) {
      int c = (n * 16 + lr) * 2;
      *(__hip_bfloat16*)(pb + (c ^ ((prow & 7) << 4))) = __float2bfloat16(sacc[n][j]);
    }
  }
  // O += P V   (4 kv-slices x 8 d-tiles)
#pragma unroll
  for (int kvs = 0; kvs < 4; ++kvs) {
    int c = kvs * 64 + lg * 16;
    bf16x8 pa = *(const bf16x8*)(pw + lr * 256 + (c ^ ((lr & 7) << 4)));
#pragma unroll
    for (int nn = 0; nn < 8; ++nn) {
      int vrow = nn * 16 + lr;
      bf16x8 vb = *(const bf16x8*)(Vs + vrow * 256 + (c ^ ((vrow & 7) << 4)));
      of[nn] = mfma16(pa, vb, of[nn]);
    }
  }
}

__global__ __launch_bounds__(256, 2) void attn_causal(
    const __hip_bfloat16* __restrict__ qkv, const __hip_bfloat16* __restrict__ vT,
    __hip_bfloat16* __restrict__ O) {
  __shared__ alignas(16) __hip_bfloat16 Ks[128 * 128];
  __shared__ alignas(16) __hip_bfloat16 Vs[128 * 128];
  __shared__ alignas(16) __hip_bfloat16 Ps[4][16 * 128];
  const int tid = threadIdx.x, lane = tid & 63, w = tid >> 6;
  const int lr = lane & 15, lg = lane >> 4;
  const int p = blockIdx.x, bh = blockIdx.y;
  const int b = bh >> 4, h = bh & 15;
  const int qtA = p, qtB = 31 - p;
  const int q0A = qtA * 64, q0B = qtB * 64;
  const int ntA = (qtA + 2) >> 1, ntB = (qtB + 2) >> 1;  // ceil((qt+1)/2)
  const float scale = 0.08838834764831845f;               // 1/sqrt(128)
  // Q fragments in registers for both q-tiles (16 rows x 128 d per wave)
  bf16x8 qfA[4], qfB[4];
  {
    const __hip_bfloat16* qpA =
        qkv + (size_t)(b * SEQ + q0A + w * 16 + lr) * NQKV + h * DH;
    const __hip_bfloat16* qpB =
        qkv + (size_t)(b * SEQ + q0B + w * 16 + lr) * NQKV + h * DH;
#pragma unroll
    for (int ks = 0; ks < 4; ++ks) {
      qfA[ks] = *(const bf16x8*)(qpA + ks * 32 + lg * 8);
      qfB[ks] = *(const bf16x8*)(qpB + ks * 32 + lg * 8);
    }
  }
  f32x4 ofA[8] = {}, ofB[8] = {};
  float mA[4], lA[4], mB[4], lB[4];
#pragma unroll
  for (int j = 0; j < 4; ++j) { mA[j] = mB[j] = -1e30f; lA[j] = lB[j] = 0.f; }
  const int myqA = q0A + w * 16 + lg * 4;
  const int myqB = q0B + w * 16 + lg * 4;
  char* pw = (char*)&Ps[w][0];

  for (int t = 0; t < ntB; ++t) {
    const int kv0 = t * 128;
    // stage K tile [128][128], source-swizzled (linear LDS dest, rule #21)
#pragma unroll
    for (int it = 0; it < 8; ++it) {
      int g = it * 256 + tid;
      int r = g >> 4, sl = g & 15;
      int ssl = sl ^ (r & 7);
      gload_lds16(qkv + (size_t)(b * SEQ + kv0 + r) * NQKV + DM + h * DH + ssl * 8,
                  (char*)Ks + (size_t)g * 16);
    }
    // stage V^T tile [128 d][128 kv]
#pragma unroll
    for (int it = 0; it < 8; ++it) {
      int g = it * 256 + tid;
      int r = g >> 4, sl = g & 15;
      int ssl = sl ^ (r & 7);
      gload_lds16(vT + (size_t)(bh * DH + r) * SEQ + kv0 + ssl * 8,
                  (char*)Vs + (size_t)g * 16);
    }
    __syncthreads();
    if (t < ntA)
      attn_tile(qfA, ofA, mA, lA, (const char*)Ks, (const char*)Vs, pw,
                lr, lg, kv0, myqA, t == ntA - 1, scale);
    attn_tile(qfB, ofB, mB, lB, (const char*)Ks, (const char*)Vs, pw,
              lr, lg, kv0, myqB, t == ntB - 1, scale);
    __syncthreads();
  }
  // epilogue: normalize + write bf16 rows for both q-tiles
#pragma unroll
  for (int j = 0; j < 4; ++j) {
    float invA = 1.0f / lA[j], invB = 1.0f / lB[j];
    __hip_bfloat16* opA =
        O + (size_t)(b * SEQ + q0A + w * 16 + lg * 4 + j) * DM + h * DH;
    __hip_bfloat16* opB =
        O + (size_t)(b * SEQ + q0B + w * 16 + lg * 4 + j) * DM + h * DH;
#pragma unroll
    for (int nn = 0; nn < 8; ++nn) {
      opA[nn * 16 + lr] = __float2bfloat16(ofA[nn][j] * invA);
      opB[nn * 16 + lr] = __float2bfloat16(ofB[nn][j] * invB);
    }
  }
}

extern "C" void kernel_launch(void* const* d_in, const int* in_sizes, int n_in,
                              void* d_out, int out_size, void* d_ws, size_t ws_size,
                              hipStream_t stream) {
  const float* x = (const float*)d_in[0];
  const float* Wqkv = (const float*)d_in[1];
  const float* Wout = (const float*)d_in[2];
  float* out = (float*)d_out;
  char* ws = (char*)d_ws;
  __hip_bfloat16* xb    = (__hip_bfloat16*)(ws + 0);
  __hip_bfloat16* wqkvT = (__hip_bfloat16*)(ws + (size_t)16777216);
  __hip_bfloat16* woutT = (__hip_bfloat16*)(ws + (size_t)41943040);
  __hip_bfloat16* qkvb  = (__hip_bfloat16*)(ws + (size_t)50331648);
  __hip_bfloat16* vT    = (__hip_bfloat16*)(ws + (size_t)100663296);
  __hip_bfloat16* ob    = (__hip_bfloat16*)(ws + (size_t)117440512);

  cast_f32_bf16<<<dim3(8192), dim3(256), 0, stream>>>(x, xb, 8388608 / 4);
  transpose_cast<<<dim3(192, 64), dim3(32, 8), 0, stream>>>(Wqkv, wqkvT, 2048, 6144);
  transpose_cast<<<dim3(64, 64), dim3(32, 8), 0, stream>>>(Wout, woutT, 2048, 2048);
  gemm_bt<0><<<dim3(48, 32), dim3(256), 0, stream>>>(xb, wqkvT, qkvb, 4096, 6144, 2048);
  transpose_v<<<dim3(64, 4, 32), dim3(32, 8), 0, stream>>>(qkvb, vT);
  attn_causal<<<dim3(16, 32), dim3(256), 0, stream>>>(qkvb, vT, ob);
  gemm_bt<1><<<dim3(16, 32), dim3(256), 0, stream>>>(ob, woutT, out, 4096, 2048, 2048);
}